// Round 14
// baseline (622.836 us; speedup 1.0000x reference)
//
#include <hip/hip_runtime.h>
#include <hip/hip_fp16.h>

#define D_IN_C 16
#define D_OUT_C 32
#define NBL 8                   // 256 dst nodes per bucket
#define NBx 256
#define NBMASK 255
#define MAXBUCK 512             // buckets = chunks = ceil(N/256) = 391
#define EPB 12800               // edges per block in hist/bin
#define CAP 8704                // per-bucket LDS edge capacity (mean 8184 + 5.8 sigma)

// ---------------------------------------------------------------------------
// K1 (new path): h16 = fp16(relu(x@w1+b1)@w2+b2), out = bl + h@wr (fp32 root
// term precomputed so agg only adds mean@wl), zero gcount.
// ---------------------------------------------------------------------------
__global__ __launch_bounds__(256) void mlp16_kernel(
    const float* __restrict__ x,
    const float* __restrict__ w1, const float* __restrict__ b1,
    const float* __restrict__ w2, const float* __restrict__ b2,
    const float* __restrict__ wr, const float* __restrict__ bl,
    __half* __restrict__ h16, float* __restrict__ out,
    int* __restrict__ gcount, int nbuck, int n_nodes) {
  __shared__ float sw1[256], sw2[256], swr[512];
  __shared__ float sb1[16], sb2[16], sbl[32];
  int t = threadIdx.x;
  sw1[t] = w1[t]; sw2[t] = w2[t];
  swr[t] = wr[t]; swr[t + 256] = wr[t + 256];
  if (t < 16) { sb1[t] = b1[t]; sb2[t] = b2[t]; }
  if (t < 32) sbl[t] = bl[t];
  __syncthreads();

  int n = blockIdx.x * 256 + t;
  if (n < nbuck) gcount[n] = 0;
  if (n >= n_nodes) return;

  float xi[16];
  const float4* xr = (const float4*)(x + (size_t)n * 16);
  float4 v0 = xr[0], v1 = xr[1], v2 = xr[2], v3 = xr[3];
  xi[0]=v0.x; xi[1]=v0.y; xi[2]=v0.z; xi[3]=v0.w;
  xi[4]=v1.x; xi[5]=v1.y; xi[6]=v1.z; xi[7]=v1.w;
  xi[8]=v2.x; xi[9]=v2.y; xi[10]=v2.z; xi[11]=v2.w;
  xi[12]=v3.x; xi[13]=v3.y; xi[14]=v3.z; xi[15]=v3.w;

  float t1[16];
#pragma unroll
  for (int j = 0; j < 16; ++j) {
    float acc = sb1[j];
#pragma unroll
    for (int kk = 0; kk < 16; ++kk) acc += xi[kk] * sw1[kk * 16 + j];
    t1[j] = fmaxf(acc, 0.0f);
  }
  float hh[16];
#pragma unroll
  for (int j = 0; j < 16; ++j) {
    float acc = sb2[j];
#pragma unroll
    for (int kk = 0; kk < 16; ++kk) acc += t1[kk] * sw2[kk * 16 + j];
    hh[j] = acc;
  }

  // fp16 row for the gather path (root path below stays fp32)
  unsigned int pk[8];
#pragma unroll
  for (int j = 0; j < 8; ++j) {
    unsigned lo = __half_as_ushort(__float2half(hh[2 * j]));
    unsigned hi = __half_as_ushort(__float2half(hh[2 * j + 1]));
    pk[j] = lo | (hi << 16);
  }
  uint4* hw = (uint4*)(h16 + (size_t)n * 16);
  hw[0] = make_uint4(pk[0], pk[1], pk[2], pk[3]);
  hw[1] = make_uint4(pk[4], pk[5], pk[6], pk[7]);

  // out = bl + h @ wr  (fp32)
  float r[32];
#pragma unroll
  for (int j = 0; j < 32; ++j) r[j] = sbl[j];
#pragma unroll
  for (int kk = 0; kk < 16; ++kk) {
    float hv = hh[kk];
#pragma unroll
    for (int j = 0; j < 32; ++j) r[j] += hv * swr[kk * 32 + j];
  }
  float4* ow = (float4*)(out + (size_t)n * 32);
#pragma unroll
  for (int q = 0; q < 8; ++q)
    ow[q] = make_float4(r[4 * q], r[4 * q + 1], r[4 * q + 2], r[4 * q + 3]);
}

// ---------------------------------------------------------------------------
// K2: per-bucket histogram (dst >> 8), LDS-aggregated per block.
// ---------------------------------------------------------------------------
__global__ __launch_bounds__(1024) void hist_kernel(
    const int* __restrict__ dst, int* __restrict__ gcount,
    int nbuck, int n_edges) {
  __shared__ int lcnt[MAXBUCK];
  int t = threadIdx.x;
  for (int i = t; i < MAXBUCK; i += 1024) lcnt[i] = 0;
  __syncthreads();
  int e0 = blockIdx.x * EPB;
  int e1 = e0 + EPB; if (e1 > n_edges) e1 = n_edges;
  for (int e = e0 + t; e < e1; e += 1024)
    atomicAdd(&lcnt[dst[e] >> NBL], 1);
  __syncthreads();
  for (int b = t; b < nbuck; b += 1024) {
    int c = lcnt[b];
    if (c) atomicAdd(&gcount[b], c);
  }
}

// ---------------------------------------------------------------------------
// K3: single-block exclusive scan over nbuck bucket counts.
// ---------------------------------------------------------------------------
__global__ __launch_bounds__(256) void scan_kernel(
    const int* __restrict__ gcount, int* __restrict__ base,
    int* __restrict__ cursor, int nbuck) {
  __shared__ int ps[256];
  int t = threadIdx.x;
  int per = (nbuck + 255) / 256;
  int beg = t * per;
  int end = beg + per; if (end > nbuck) end = nbuck;
  int sum = 0;
  for (int i = beg; i < end; ++i) sum += gcount[i];
  ps[t] = sum;
  __syncthreads();
#pragma unroll
  for (int off = 1; off < 256; off <<= 1) {
    int add = (t >= off) ? ps[t - off] : 0;
    __syncthreads();
    ps[t] += add;
    __syncthreads();
  }
  int run = ps[t] - sum;
  for (int i = beg; i < end; ++i) {
    base[i] = run;
    cursor[i] = run;
    run += gcount[i];
  }
  if (t == 255) base[nbuck] = ps[255];
}

// ---------------------------------------------------------------------------
// K4: bin edges by dst-bucket. pack = (src << 8) | (dst & 255).
// ---------------------------------------------------------------------------
__global__ __launch_bounds__(1024) void bin_kernel(
    const int* __restrict__ src, const int* __restrict__ dst,
    int* __restrict__ cursor, unsigned int* __restrict__ ebuf,
    int nbuck, int n_edges) {
  __shared__ int lcnt[MAXBUCK];
  __shared__ int lspan[MAXBUCK];
  int t = threadIdx.x;
  for (int i = t; i < MAXBUCK; i += 1024) lcnt[i] = 0;
  __syncthreads();
  int e0 = blockIdx.x * EPB;
  int e1 = e0 + EPB; if (e1 > n_edges) e1 = n_edges;
  for (int e = e0 + t; e < e1; e += 1024)
    atomicAdd(&lcnt[dst[e] >> NBL], 1);
  __syncthreads();
  for (int b = t; b < nbuck; b += 1024) {
    int c = lcnt[b];
    lspan[b] = c ? atomicAdd(&cursor[b], c) : 0;
    lcnt[b] = 0;
  }
  __syncthreads();
  for (int e = e0 + t; e < e1; e += 1024) {
    int d = dst[e];
    int b = d >> NBL;
    int r = atomicAdd(&lcnt[b], 1);
    ebuf[lspan[b] + r] =
        ((unsigned int)src[e] << NBL) | (unsigned int)(d & NBMASK);
  }
}

// ---------------------------------------------------------------------------
// K5: TILED-STREAMING aggregate. Rounds 3-13 established an empirical law:
// random 64B line requests are serviced at ~35 CU-cycles/line regardless of
// concurrency offered (asm-batched, DMA), hit locus (two-pass L2-resident:
// FETCH 93->28MB, per-edge time UNCHANGED), or path => floor ~182us for any
// gather scheme. This kernel issues ZERO random global requests:
//  - block = one 256-node dst bucket (~8.2K edges)
//  - LDS counting-sort of the block's edges by 256-node src-chunk; entries
//    compress to u16 (srcLocal<<8 | dstLocal), chunk id is positional
//  - stream all 391 fp16 h-chunks (8KB, coalesced global_load_lds,
//    double-buffered) and resolve each chunk's edges from LDS
//  - epilogue: out += mean @ wl (root term pre-added by mlp16)
// LDS ~59KB (under the 64KB static cap), 2 blocks/CU.
// ---------------------------------------------------------------------------
__global__ __launch_bounds__(256) void agg_tiled_kernel(
    const __half* __restrict__ h16, const unsigned int* __restrict__ ebuf,
    const int* __restrict__ base, const float* __restrict__ wl,
    float* __restrict__ out, int nbuck, int n_nodes) {
  __shared__ unsigned short entS[CAP];            // 17408 B
  __shared__ __align__(16) __half bufs[2 * 4096]; // 16384 B (2 x 8KB chunks)
  __shared__ float ssum[NBx * 16];                // 16384 B
  __shared__ int   scnt[NBx];                     // 1024 B
  __shared__ int   ccnt[MAXBUCK];                 // 2048 B (hist -> cursor)
  __shared__ int   coff[MAXBUCK + 1];             // 2052 B
  __shared__ float swl[512];                      // 2048 B

  int t = threadIdx.x;
  int b = blockIdx.x;
  int nch = nbuck;            // src-chunks share the 256-node granularity

  swl[t] = wl[t]; swl[t + 256] = wl[t + 256];
#pragma unroll
  for (int i = t; i < NBx * 16; i += 256) ssum[i] = 0.0f;
  if (t < NBx) scnt[t] = 0;
  for (int i = t; i < MAXBUCK; i += 256) ccnt[i] = 0;
  __syncthreads();

  int beg = base[b];
  int end = base[b + 1];
  int ne = end - beg; if (ne > CAP) ne = CAP;

  // pass 1: histogram by src-chunk (chunk = ee >> 16)
  for (int i = t; i < ne; i += 256)
    atomicAdd(&ccnt[ebuf[beg + i] >> 16], 1);
  __syncthreads();
  // serial exclusive scan (391 elements)
  if (t == 0) {
    int run = 0;
    for (int c = 0; c < nch; ++c) {
      int cc = ccnt[c];
      coff[c] = run;
      ccnt[c] = run;        // reuse as scatter cursor
      run += cc;
    }
    coff[nch] = run;
  }
  __syncthreads();
  // pass 2: scatter compressed entries in chunk order
  for (int i = t; i < ne; i += 256) {
    unsigned int ee = ebuf[beg + i];
    int c = (int)(ee >> 16);
    int r = atomicAdd(&ccnt[c], 1);
    entS[r] = (unsigned short)(ee & 0xFFFFu);
  }
  __syncthreads();

  int g = t >> 4;     // 16 groups of 16 lanes
  int k = t & 15;

  // overflow edges (> CAP, ~never): correct slow path, random gather
  for (int p = beg + CAP + g; p < end; p += 16) {
    unsigned int ee = ebuf[p];
    unsigned int s = ee >> NBL;
    int dl = (int)(ee & NBMASK);
    float v = __half2float(h16[(size_t)s * 16 + k]);
    atomicAdd(&ssum[dl * 16 + k], v);
    if (k == 0) atomicAdd(&scnt[dl], 1);
  }

  // chunk streaming: coalesced global_load_lds, double-buffered
  const char* hb = (const char*)h16;
  int wlane = t >> 6;             // wave id 0..3
  // load chunk 0 into buf 0
  {
    unsigned cbase = 0u;
#pragma unroll
    for (int i = 0; i < 2; ++i) {
      const void* gp = (const void*)(hb + cbase + i * 4096 + t * 16);
      char* lp = ((char*)bufs) + i * 4096 + wlane * 1024;
      __builtin_amdgcn_global_load_lds(
          (const __attribute__((address_space(1))) void*)gp,
          (__attribute__((address_space(3))) void*)lp, 16, 0, 0);
    }
  }
  asm volatile("s_waitcnt vmcnt(0)" ::: "memory");
  __syncthreads();

  for (int c = 0; c < nch; ++c) {
    if (c + 1 < nch) {
      unsigned cbase = (unsigned)(c + 1) * (NBx * 32);
      int bsel = (c + 1) & 1;
#pragma unroll
      for (int i = 0; i < 2; ++i) {
        const void* gp = (const void*)(hb + cbase + i * 4096 + t * 16);
        char* lp = ((char*)bufs) + bsel * 8192 + i * 4096 + wlane * 1024;
        __builtin_amdgcn_global_load_lds(
            (const __attribute__((address_space(1))) void*)gp,
            (__attribute__((address_space(3))) void*)lp, 16, 0, 0);
      }
    }
    const __half* hbuf = bufs + (c & 1) * 4096;
    int cb = coff[c], ce = coff[c + 1];
    for (int i = cb + g; i < ce; i += 16) {
      unsigned short e2 = entS[i];          // broadcast within group
      int sl = e2 >> 8;
      int dl = e2 & 255;
      float v = __half2float(hbuf[sl * 16 + k]);
      atomicAdd(&ssum[dl * 16 + k], v);
      if (k == 0) atomicAdd(&scnt[dl], 1);
    }
    asm volatile("s_waitcnt vmcnt(0)" ::: "memory");
    __syncthreads();
  }

  // epilogue: out += mean @ wl
  int j = t & 31;
  for (int nl = t >> 5; nl < NBx; nl += 8) {
    int n = b * NBx + nl;
    if (n >= n_nodes) break;
    float inv = 1.0f / fmaxf((float)scnt[nl], 1.0f);
    float acc = 0.0f;
#pragma unroll
    for (int kk = 0; kk < 16; ++kk)
      acc += ssum[nl * 16 + kk] * inv * swl[kk * 32 + j];
    out[(size_t)n * 32 + j] += acc;
  }
}

// ---------------------------------------------------------------------------
// FALLBACK PATH (verified atomic kernels) — used only if ws too small or
// bucket table exceeds MAXBUCK.
// ---------------------------------------------------------------------------
__global__ __launch_bounds__(256) void mlp_kernel(
    const float* __restrict__ x,
    const float* __restrict__ w1, const float* __restrict__ b1,
    const float* __restrict__ w2, const float* __restrict__ b2,
    float* __restrict__ h, float* __restrict__ summed, int* __restrict__ cnt,
    int n_nodes) {
  __shared__ float sw1[256];
  __shared__ float sw2[256];
  __shared__ float sb1[16];
  __shared__ float sb2[16];
  int t = threadIdx.x;
  sw1[t] = w1[t];
  sw2[t] = w2[t];
  if (t < 16) { sb1[t] = b1[t]; sb2[t] = b2[t]; }
  __syncthreads();

  int n = blockIdx.x * blockDim.x + t;
  if (n >= n_nodes) return;

  float xi[16];
  const float4* xr = (const float4*)(x + (size_t)n * 16);
  float4 v0 = xr[0], v1 = xr[1], v2 = xr[2], v3 = xr[3];
  xi[0]=v0.x; xi[1]=v0.y; xi[2]=v0.z; xi[3]=v0.w;
  xi[4]=v1.x; xi[5]=v1.y; xi[6]=v1.z; xi[7]=v1.w;
  xi[8]=v2.x; xi[9]=v2.y; xi[10]=v2.z; xi[11]=v2.w;
  xi[12]=v3.x; xi[13]=v3.y; xi[14]=v3.z; xi[15]=v3.w;

  float t1[16];
#pragma unroll
  for (int j = 0; j < 16; ++j) {
    float acc = sb1[j];
#pragma unroll
    for (int kk = 0; kk < 16; ++kk) acc += xi[kk] * sw1[kk * 16 + j];
    t1[j] = fmaxf(acc, 0.0f);
  }
  float hh[16];
#pragma unroll
  for (int j = 0; j < 16; ++j) {
    float acc = sb2[j];
#pragma unroll
    for (int kk = 0; kk < 16; ++kk) acc += t1[kk] * sw2[kk * 16 + j];
    hh[j] = acc;
  }

  float4* hw = (float4*)(h + (size_t)n * 16);
  hw[0] = make_float4(hh[0], hh[1], hh[2], hh[3]);
  hw[1] = make_float4(hh[4], hh[5], hh[6], hh[7]);
  hw[2] = make_float4(hh[8], hh[9], hh[10], hh[11]);
  hw[3] = make_float4(hh[12], hh[13], hh[14], hh[15]);

  cnt[n] = 0;
  float4* sz = (float4*)(summed + (size_t)n * 16);
  float4 z = make_float4(0.f, 0.f, 0.f, 0.f);
  sz[0] = z; sz[1] = z; sz[2] = z; sz[3] = z;
}

__global__ __launch_bounds__(256) void scatter_kernel(
    const int* __restrict__ src, const int* __restrict__ dst,
    const float* __restrict__ h, float* __restrict__ summed,
    int* __restrict__ cnt, long long n_edges) {
  long long tid = (long long)blockIdx.x * blockDim.x + threadIdx.x;
  long long e = tid >> 4;
  int k = (int)(tid & 15);
  if (e >= n_edges) return;
  int s = src[e];
  int d = dst[e];
  float val = h[(size_t)s * 16 + k];
  atomicAdd(&summed[(size_t)d * 16 + k], val);
  if (k == 0) atomicAdd(&cnt[d], 1);
}

__global__ __launch_bounds__(256) void out_kernel(
    const float* __restrict__ h, const float* __restrict__ summed,
    const int* __restrict__ cnt,
    const float* __restrict__ wl, const float* __restrict__ bl,
    const float* __restrict__ wr, float* __restrict__ out, int n_nodes) {
  __shared__ float swl[512];
  __shared__ float swr[512];
  __shared__ float sbl[32];
  int t = threadIdx.x;
  for (int i = t; i < 512; i += 256) { swl[i] = wl[i]; swr[i] = wr[i]; }
  if (t < 32) sbl[t] = bl[t];
  __syncthreads();

  int gid = blockIdx.x * 256 + t;
  int n = gid >> 5;
  int j = gid & 31;
  if (n >= n_nodes) return;

  float inv = 1.0f / fmaxf((float)cnt[n], 1.0f);
  const float* hr = h + (size_t)n * 16;
  const float* sr = summed + (size_t)n * 16;
  float acc = sbl[j];
#pragma unroll
  for (int kk = 0; kk < 16; ++kk) {
    acc += sr[kk] * inv * swl[kk * 32 + j] + hr[kk] * swr[kk * 32 + j];
  }
  out[(size_t)n * 32 + j] = acc;
}

// ---------------------------------------------------------------------------
extern "C" void kernel_launch(void* const* d_in, const int* in_sizes, int n_in,
                              void* d_out, int out_size, void* d_ws, size_t ws_size,
                              hipStream_t stream) {
  const float* x  = (const float*)d_in[0];
  const int* eidx = (const int*)d_in[1];
  const float* w1 = (const float*)d_in[2];
  const float* b1 = (const float*)d_in[3];
  const float* w2 = (const float*)d_in[4];
  const float* b2 = (const float*)d_in[5];
  const float* wl = (const float*)d_in[6];
  const float* bl = (const float*)d_in[7];
  const float* wr = (const float*)d_in[8];
  float* out = (float*)d_out;

  const int n_nodes = in_sizes[0] / D_IN_C;             // 100000
  const long long n_edges = (long long)in_sizes[1] / 2; // 3200000
  const int* src = eidx;
  const int* dst = eidx + n_edges;

  const int node_blocks = (n_nodes + 255) / 256;         // 391
  const int nbuck = (n_nodes + NBx - 1) / NBx;           // 391
  const int padrows = nbuck * NBx;                       // 100096
  const int epb_blocks = (int)((n_edges + EPB - 1) / EPB); // 250

  // New-path workspace layout.
  __half*       h16    = (__half*)d_ws;                        // padrows*16
  int*          gcount = (int*)((char*)d_ws + (size_t)padrows * 32);
  int*          cursor = gcount + nbuck;
  int*          basep  = cursor + nbuck;                       // nbuck+1
  unsigned int* ebuf   = (unsigned int*)(basep + nbuck + 1);   // E u32

  size_t need = (size_t)padrows * 32 + (3ull * nbuck + 1) * 4
              + (size_t)n_edges * 4;

  if (ws_size >= need && nbuck <= MAXBUCK) {
    // ---- counting sort by dst-bucket + tiled streaming aggregation ----
    mlp16_kernel<<<node_blocks, 256, 0, stream>>>(
        x, w1, b1, w2, b2, wr, bl, h16, out, gcount, nbuck, n_nodes);
    hist_kernel<<<epb_blocks, 1024, 0, stream>>>(dst, gcount, nbuck,
                                                 (int)n_edges);
    scan_kernel<<<1, 256, 0, stream>>>(gcount, basep, cursor, nbuck);
    bin_kernel<<<epb_blocks, 1024, 0, stream>>>(src, dst, cursor, ebuf,
                                                nbuck, (int)n_edges);
    agg_tiled_kernel<<<nbuck, 256, 0, stream>>>(h16, ebuf, basep, wl, out,
                                                nbuck, n_nodes);
  } else {
    // ---- fallback: verified atomic path ----
    float* h      = (float*)d_ws;
    float* summed = h + (size_t)n_nodes * 16;
    int*   fcnt   = (int*)(summed + (size_t)n_nodes * 16);
    mlp_kernel<<<node_blocks, 256, 0, stream>>>(
        x, w1, b1, w2, b2, h, summed, fcnt, n_nodes);
    {
      long long total = n_edges * 16;
      int blocks = (int)((total + 255) / 256);
      scatter_kernel<<<blocks, 256, 0, stream>>>(src, dst, h, summed, fcnt,
                                                 n_edges);
    }
    {
      long long total = (long long)n_nodes * 32;
      int blocks = (int)((total + 255) / 256);
      out_kernel<<<blocks, 256, 0, stream>>>(h, summed, fcnt, wl, bl, wr,
                                             out, n_nodes);
    }
  }
}

// Round 15
// 614.095 us; speedup vs baseline: 1.0142x; 1.0142x over previous
//
#include <hip/hip_runtime.h>
#include <hip/hip_fp16.h>

#define D_IN_C 16
#define D_OUT_C 32
#define NBL 8                   // 256 dst nodes per bucket; 256-row src chunks
#define NBx 256
#define NBMASK 255
#define MAXBUCK 512             // >= nbuck = ceil(N/256) = 391
#define EPB 12800               // edges per block in hist/bin
#define CAPS 9216               // per-bucket edge cap (mean 8184, ~11 sigma)

// ---------------------------------------------------------------------------
// K1: h16 = fp16(relu(x@w1+b1)@w2+b2), out = bl + h@wr (fp32 root term
// precomputed so agg only adds mean@wl), zero gcount. [validated round 14:
// passed, absmax 0.0039]
// ---------------------------------------------------------------------------
__global__ __launch_bounds__(256) void mlp16_kernel(
    const float* __restrict__ x,
    const float* __restrict__ w1, const float* __restrict__ b1,
    const float* __restrict__ w2, const float* __restrict__ b2,
    const float* __restrict__ wr, const float* __restrict__ bl,
    __half* __restrict__ h16, float* __restrict__ out,
    int* __restrict__ gcount, int nbuck, int n_nodes) {
  __shared__ float sw1[256], sw2[256], swr[512];
  __shared__ float sb1[16], sb2[16], sbl[32];
  int t = threadIdx.x;
  sw1[t] = w1[t]; sw2[t] = w2[t];
  swr[t] = wr[t]; swr[t + 256] = wr[t + 256];
  if (t < 16) { sb1[t] = b1[t]; sb2[t] = b2[t]; }
  if (t < 32) sbl[t] = bl[t];
  __syncthreads();

  int n = blockIdx.x * 256 + t;
  if (n < nbuck) gcount[n] = 0;
  if (n >= n_nodes) return;

  float xi[16];
  const float4* xr = (const float4*)(x + (size_t)n * 16);
  float4 v0 = xr[0], v1 = xr[1], v2 = xr[2], v3 = xr[3];
  xi[0]=v0.x; xi[1]=v0.y; xi[2]=v0.z; xi[3]=v0.w;
  xi[4]=v1.x; xi[5]=v1.y; xi[6]=v1.z; xi[7]=v1.w;
  xi[8]=v2.x; xi[9]=v2.y; xi[10]=v2.z; xi[11]=v2.w;
  xi[12]=v3.x; xi[13]=v3.y; xi[14]=v3.z; xi[15]=v3.w;

  float t1[16];
#pragma unroll
  for (int j = 0; j < 16; ++j) {
    float acc = sb1[j];
#pragma unroll
    for (int kk = 0; kk < 16; ++kk) acc += xi[kk] * sw1[kk * 16 + j];
    t1[j] = fmaxf(acc, 0.0f);
  }
  float hh[16];
#pragma unroll
  for (int j = 0; j < 16; ++j) {
    float acc = sb2[j];
#pragma unroll
    for (int kk = 0; kk < 16; ++kk) acc += t1[kk] * sw2[kk * 16 + j];
    hh[j] = acc;
  }

  unsigned int pk[8];
#pragma unroll
  for (int j = 0; j < 8; ++j) {
    unsigned lo = __half_as_ushort(__float2half(hh[2 * j]));
    unsigned hi = __half_as_ushort(__float2half(hh[2 * j + 1]));
    pk[j] = lo | (hi << 16);
  }
  uint4* hw = (uint4*)(h16 + (size_t)n * 16);
  hw[0] = make_uint4(pk[0], pk[1], pk[2], pk[3]);
  hw[1] = make_uint4(pk[4], pk[5], pk[6], pk[7]);

  float r[32];
#pragma unroll
  for (int j = 0; j < 32; ++j) r[j] = sbl[j];
#pragma unroll
  for (int kk = 0; kk < 16; ++kk) {
    float hv = hh[kk];
#pragma unroll
    for (int j = 0; j < 32; ++j) r[j] += hv * swr[kk * 32 + j];
  }
  float4* ow = (float4*)(out + (size_t)n * 32);
#pragma unroll
  for (int q = 0; q < 8; ++q)
    ow[q] = make_float4(r[4 * q], r[4 * q + 1], r[4 * q + 2], r[4 * q + 3]);
}

// ---------------------------------------------------------------------------
// K2: per-bucket histogram (dst >> 8), LDS-aggregated per block.
// ---------------------------------------------------------------------------
__global__ __launch_bounds__(1024) void hist_kernel(
    const int* __restrict__ dst, int* __restrict__ gcount,
    int nbuck, int n_edges) {
  __shared__ int lcnt[MAXBUCK];
  int t = threadIdx.x;
  for (int i = t; i < MAXBUCK; i += 1024) lcnt[i] = 0;
  __syncthreads();
  int e0 = blockIdx.x * EPB;
  int e1 = e0 + EPB; if (e1 > n_edges) e1 = n_edges;
  for (int e = e0 + t; e < e1; e += 1024)
    atomicAdd(&lcnt[dst[e] >> NBL], 1);
  __syncthreads();
  for (int b = t; b < nbuck; b += 1024) {
    int c = lcnt[b];
    if (c) atomicAdd(&gcount[b], c);
  }
}

// ---------------------------------------------------------------------------
// K3: single-block exclusive scan over nbuck bucket counts.
// ---------------------------------------------------------------------------
__global__ __launch_bounds__(256) void scan_kernel(
    const int* __restrict__ gcount, int* __restrict__ base,
    int* __restrict__ cursor, int nbuck) {
  __shared__ int ps[256];
  int t = threadIdx.x;
  int per = (nbuck + 255) / 256;
  int beg = t * per;
  int end = beg + per; if (end > nbuck) end = nbuck;
  int sum = 0;
  for (int i = beg; i < end; ++i) sum += gcount[i];
  ps[t] = sum;
  __syncthreads();
#pragma unroll
  for (int off = 1; off < 256; off <<= 1) {
    int add = (t >= off) ? ps[t - off] : 0;
    __syncthreads();
    ps[t] += add;
    __syncthreads();
  }
  int run = ps[t] - sum;
  for (int i = beg; i < end; ++i) {
    base[i] = run;
    cursor[i] = run;
    run += gcount[i];
  }
  if (t == 255) base[nbuck] = ps[255];
}

// ---------------------------------------------------------------------------
// K4: bin edges by dst-bucket. pack = (src << 8) | (dst & 255), 25 bits.
// ---------------------------------------------------------------------------
__global__ __launch_bounds__(1024) void bin_kernel(
    const int* __restrict__ src, const int* __restrict__ dst,
    int* __restrict__ cursor, unsigned int* __restrict__ ebuf,
    int nbuck, int n_edges) {
  __shared__ int lcnt[MAXBUCK];
  __shared__ int lspan[MAXBUCK];
  int t = threadIdx.x;
  for (int i = t; i < MAXBUCK; i += 1024) lcnt[i] = 0;
  __syncthreads();
  int e0 = blockIdx.x * EPB;
  int e1 = e0 + EPB; if (e1 > n_edges) e1 = n_edges;
  for (int e = e0 + t; e < e1; e += 1024)
    atomicAdd(&lcnt[dst[e] >> NBL], 1);
  __syncthreads();
  for (int b = t; b < nbuck; b += 1024) {
    int c = lcnt[b];
    lspan[b] = c ? atomicAdd(&cursor[b], c) : 0;
    lcnt[b] = 0;
  }
  __syncthreads();
  for (int e = e0 + t; e < e1; e += 1024) {
    int d = dst[e];
    int b = d >> NBL;
    int r = atomicAdd(&lcnt[b], 1);
    ebuf[lspan[b] + r] =
        ((unsigned int)src[e] << NBL) | (unsigned int)(d & NBMASK);
  }
}

// ---------------------------------------------------------------------------
// K4b (NEW): per-bucket chunk-sort. Sorts each bucket's edges by src-chunk
// (ee>>16) via LDS counting sort; writes compressed u16 (srcLocal<<8|dstLocal)
// IN PLACE over the lower half of the bucket's u32 segment (all reads finish
// before the dump), plus per-chunk offsets + overflow flag to coffG.
// Coalesced global reads/writes only.
// ---------------------------------------------------------------------------
__global__ __launch_bounds__(256) void csort_kernel(
    unsigned int* __restrict__ ebuf, const int* __restrict__ base,
    int* __restrict__ coffG, int nch) {
  __shared__ unsigned short eS2[CAPS];   // 18432 B
  __shared__ int ccnt[392];
  __shared__ int coffL[393];
  int t = threadIdx.x;
  int b = blockIdx.x;
  int beg = base[b], end = base[b + 1];
  int ne = end - beg;

  for (int i = t; i < 392; i += 256) ccnt[i] = 0;
  __syncthreads();

  if (ne > CAPS) {                       // ~11 sigma; agg uses gather fallback
    if (t == 0) coffG[b * 400 + 399] = 1;
    return;
  }
  // hist by chunk
  for (int i = t; i < ne; i += 256)
    atomicAdd(&ccnt[ebuf[beg + i] >> 16], 1);
  __syncthreads();
  if (t == 0) {
    int run = 0;
    for (int c = 0; c < nch; ++c) {
      int cc = ccnt[c];
      coffL[c] = run;
      ccnt[c] = run;                     // reuse as cursor
      run += cc;
    }
    coffL[nch] = run;
  }
  __syncthreads();
  // scatter into LDS u16
  for (int i = t; i < ne; i += 256) {
    unsigned int ee = ebuf[beg + i];
    int c = (int)(ee >> 16);
    int r = atomicAdd(&ccnt[c], 1);
    eS2[r] = (unsigned short)(ee & 0xFFFFu);
  }
  __syncthreads();
  // dump sorted u16 list in place (byte range [4*beg, 4*beg+2*ne))
  unsigned short* d16 = (unsigned short*)ebuf + (size_t)2 * beg;
  unsigned int* d32 = (unsigned int*)d16;
  int np = ne >> 1;
  for (int i = t; i < np; i += 256)
    d32[i] = (unsigned)eS2[2 * i] | ((unsigned)eS2[2 * i + 1] << 16);
  if ((ne & 1) && t == 0) d16[ne - 1] = eS2[ne - 1];
  for (int i = t; i <= nch; i += 256) coffG[b * 400 + i] = coffL[i];
  if (t == 0) coffG[b * 400 + 399] = 0;
}

// ---------------------------------------------------------------------------
// K5: pipelined streaming aggregate. Fixes vs round 14 (494us):
//  (1) RAW s_barrier + counted vmcnt(2): __syncthreads() made hipcc emit
//      vmcnt(0) before every barrier, draining the prefetch each of 391
//      rounds (the measured serialization). Raw barrier + hand waits keep
//      chunk c+1's loads in flight across the barrier (T3+T4 pattern).
//  (2) edges pre-sorted by csort and staged ONCE into LDS as u16 -> the
//      K-loop's only VMEM is the 2 global_load_lds (nothing for the
//      compiler to drain against).
//  (3) LDS 55.8KB -> 2 blocks/CU for cross-block latency overlap.
// Protocol/round: issue(c+1) ; vmcnt(2) [my chunk-c ops retired] ; s_barrier
// [everyone's c-ops retired] ; process c from LDS ; s_barrier [safe to
// overwrite buf(c&1) next round].
// ---------------------------------------------------------------------------
__global__ __launch_bounds__(256) void agg_stream_kernel(
    const __half* __restrict__ h16, const unsigned int* __restrict__ ebuf,
    const int* __restrict__ base, const int* __restrict__ coffG,
    const float* __restrict__ wl, float* __restrict__ out,
    int nch, int n_nodes) {
  __shared__ unsigned short entL[CAPS];            // 18432 B
  __shared__ __align__(16) __half bufs[2 * 4096];  // 16384 B
  __shared__ float ssum[NBx * 16];                 // 16384 B
  __shared__ int   scnt[NBx];                      // 1024 B
  __shared__ int   coff[393];                      // 1572 B
  __shared__ float swl[512];                       // 2048 B

  int t = threadIdx.x;
  int b = blockIdx.x;
  int beg = base[b], end = base[b + 1];
  int ne = end - beg;

  swl[t] = wl[t]; swl[t + 256] = wl[t + 256];
#pragma unroll
  for (int i = t; i < NBx * 16; i += 256) ssum[i] = 0.0f;
  scnt[t] = 0;
  int flag = coffG[b * 400 + 399];
  for (int i = t; i <= nch; i += 256) coff[i] = coffG[b * 400 + i];
  if (!flag) {
    const unsigned short* s16 = (const unsigned short*)ebuf + (size_t)2 * beg;
    const unsigned int* s32 = (const unsigned int*)s16;
    int np = ne >> 1;
    for (int i = t; i < np; i += 256) {
      unsigned v = s32[i];
      entL[2 * i] = (unsigned short)(v & 0xFFFFu);
      entL[2 * i + 1] = (unsigned short)(v >> 16);
    }
    if ((ne & 1) && t == 0) entL[ne - 1] = s16[ne - 1];
  }
  __syncthreads();

  int g = t >> 4, k = t & 15;
  int wid = t >> 6, lane = t & 63;

  if (flag) {
    // overflow bucket (~never): cooperative random gather on intact u32 list
    for (int p = beg + g; p < end; p += 16) {
      unsigned int ee = ebuf[p];
      unsigned int s = ee >> NBL;
      int dl = (int)(ee & NBMASK);
      float v = __half2float(h16[(size_t)s * 16 + k]);
      atomicAdd(&ssum[dl * 16 + k], v);
      if (k == 0) atomicAdd(&scnt[dl], 1);
    }
    __syncthreads();
  } else {
    const char* hb = (const char*)h16;
#define ISSUE_CHUNK(c_, bi_)                                                  \
  {                                                                           \
    unsigned cbase_ = (unsigned)(c_) * 8192u;                                 \
    _Pragma("unroll")                                                         \
    for (int i2 = 0; i2 < 2; ++i2) {                                          \
      const void* gp_ = (const void*)(hb + cbase_ +                           \
          (unsigned)(wid * 2048 + i2 * 1024) + (unsigned)(lane * 16));        \
      char* lp_ = ((char*)bufs) + (bi_) * 8192 + wid * 2048 + i2 * 1024;      \
      __builtin_amdgcn_global_load_lds(                                       \
          (const __attribute__((address_space(1))) void*)gp_,                 \
          (__attribute__((address_space(3))) void*)lp_, 16, 0, 0);            \
    }                                                                         \
  }
    ISSUE_CHUNK(0, 0);
    for (int c = 0; c < nch; ++c) {
      if (c + 1 < nch) {
        ISSUE_CHUNK(c + 1, (c + 1) & 1);
        asm volatile("s_waitcnt vmcnt(2)" ::: "memory");
      } else {
        asm volatile("s_waitcnt vmcnt(0)" ::: "memory");
      }
      __builtin_amdgcn_s_barrier();
      const __half* hbuf = bufs + (c & 1) * 4096;
      int cb = coff[c], ce = coff[c + 1];
      for (int i = cb + g; i < ce; i += 16) {
        unsigned short e2 = entL[i];        // broadcast within group
        int sl = e2 >> 8;
        int dl = e2 & 255;
        float v = __half2float(hbuf[sl * 16 + k]);
        atomicAdd(&ssum[dl * 16 + k], v);
        if (k == 0) atomicAdd(&scnt[dl], 1);
      }
      __builtin_amdgcn_s_barrier();
    }
#undef ISSUE_CHUNK
    __syncthreads();   // full drain before epilogue reads ssum
  }

  // epilogue: out += mean @ wl
  int j = t & 31;
  for (int nl = t >> 5; nl < NBx; nl += 8) {
    int n = b * NBx + nl;
    if (n >= n_nodes) break;
    float inv = 1.0f / fmaxf((float)scnt[nl], 1.0f);
    float acc = 0.0f;
#pragma unroll
    for (int kk = 0; kk < 16; ++kk)
      acc += ssum[nl * 16 + kk] * inv * swl[kk * 32 + j];
    out[(size_t)n * 32 + j] += acc;
  }
}

// ---------------------------------------------------------------------------
// FALLBACK PATH (verified atomic kernels) — used only if ws too small or
// bucket table exceeds MAXBUCK.
// ---------------------------------------------------------------------------
__global__ __launch_bounds__(256) void mlp_kernel(
    const float* __restrict__ x,
    const float* __restrict__ w1, const float* __restrict__ b1,
    const float* __restrict__ w2, const float* __restrict__ b2,
    float* __restrict__ h, float* __restrict__ summed, int* __restrict__ cnt,
    int n_nodes) {
  __shared__ float sw1[256];
  __shared__ float sw2[256];
  __shared__ float sb1[16];
  __shared__ float sb2[16];
  int t = threadIdx.x;
  sw1[t] = w1[t];
  sw2[t] = w2[t];
  if (t < 16) { sb1[t] = b1[t]; sb2[t] = b2[t]; }
  __syncthreads();

  int n = blockIdx.x * blockDim.x + t;
  if (n >= n_nodes) return;

  float xi[16];
  const float4* xr = (const float4*)(x + (size_t)n * 16);
  float4 v0 = xr[0], v1 = xr[1], v2 = xr[2], v3 = xr[3];
  xi[0]=v0.x; xi[1]=v0.y; xi[2]=v0.z; xi[3]=v0.w;
  xi[4]=v1.x; xi[5]=v1.y; xi[6]=v1.z; xi[7]=v1.w;
  xi[8]=v2.x; xi[9]=v2.y; xi[10]=v2.z; xi[11]=v2.w;
  xi[12]=v3.x; xi[13]=v3.y; xi[14]=v3.z; xi[15]=v3.w;

  float t1[16];
#pragma unroll
  for (int j = 0; j < 16; ++j) {
    float acc = sb1[j];
#pragma unroll
    for (int kk = 0; kk < 16; ++kk) acc += xi[kk] * sw1[kk * 16 + j];
    t1[j] = fmaxf(acc, 0.0f);
  }
  float hh[16];
#pragma unroll
  for (int j = 0; j < 16; ++j) {
    float acc = sb2[j];
#pragma unroll
    for (int kk = 0; kk < 16; ++kk) acc += t1[kk] * sw2[kk * 16 + j];
    hh[j] = acc;
  }

  float4* hw = (float4*)(h + (size_t)n * 16);
  hw[0] = make_float4(hh[0], hh[1], hh[2], hh[3]);
  hw[1] = make_float4(hh[4], hh[5], hh[6], hh[7]);
  hw[2] = make_float4(hh[8], hh[9], hh[10], hh[11]);
  hw[3] = make_float4(hh[12], hh[13], hh[14], hh[15]);

  cnt[n] = 0;
  float4* sz = (float4*)(summed + (size_t)n * 16);
  float4 z = make_float4(0.f, 0.f, 0.f, 0.f);
  sz[0] = z; sz[1] = z; sz[2] = z; sz[3] = z;
}

__global__ __launch_bounds__(256) void scatter_kernel(
    const int* __restrict__ src, const int* __restrict__ dst,
    const float* __restrict__ h, float* __restrict__ summed,
    int* __restrict__ cnt, long long n_edges) {
  long long tid = (long long)blockIdx.x * blockDim.x + threadIdx.x;
  long long e = tid >> 4;
  int k = (int)(tid & 15);
  if (e >= n_edges) return;
  int s = src[e];
  int d = dst[e];
  float val = h[(size_t)s * 16 + k];
  atomicAdd(&summed[(size_t)d * 16 + k], val);
  if (k == 0) atomicAdd(&cnt[d], 1);
}

__global__ __launch_bounds__(256) void out_kernel(
    const float* __restrict__ h, const float* __restrict__ summed,
    const int* __restrict__ cnt,
    const float* __restrict__ wl, const float* __restrict__ bl,
    const float* __restrict__ wr, float* __restrict__ out, int n_nodes) {
  __shared__ float swl[512];
  __shared__ float swr[512];
  __shared__ float sbl[32];
  int t = threadIdx.x;
  for (int i = t; i < 512; i += 256) { swl[i] = wl[i]; swr[i] = wr[i]; }
  if (t < 32) sbl[t] = bl[t];
  __syncthreads();

  int gid = blockIdx.x * 256 + t;
  int n = gid >> 5;
  int j = gid & 31;
  if (n >= n_nodes) return;

  float inv = 1.0f / fmaxf((float)cnt[n], 1.0f);
  const float* hr = h + (size_t)n * 16;
  const float* sr = summed + (size_t)n * 16;
  float acc = sbl[j];
#pragma unroll
  for (int kk = 0; kk < 16; ++kk) {
    acc += sr[kk] * inv * swl[kk * 32 + j] + hr[kk] * swr[kk * 32 + j];
  }
  out[(size_t)n * 32 + j] = acc;
}

// ---------------------------------------------------------------------------
extern "C" void kernel_launch(void* const* d_in, const int* in_sizes, int n_in,
                              void* d_out, int out_size, void* d_ws, size_t ws_size,
                              hipStream_t stream) {
  const float* x  = (const float*)d_in[0];
  const int* eidx = (const int*)d_in[1];
  const float* w1 = (const float*)d_in[2];
  const float* b1 = (const float*)d_in[3];
  const float* w2 = (const float*)d_in[4];
  const float* b2 = (const float*)d_in[5];
  const float* wl = (const float*)d_in[6];
  const float* bl = (const float*)d_in[7];
  const float* wr = (const float*)d_in[8];
  float* out = (float*)d_out;

  const int n_nodes = in_sizes[0] / D_IN_C;             // 100000
  const long long n_edges = (long long)in_sizes[1] / 2; // 3200000
  const int* src = eidx;
  const int* dst = eidx + n_edges;

  const int node_blocks = (n_nodes + 255) / 256;         // 391
  const int nbuck = (n_nodes + NBx - 1) / NBx;           // 391 (buckets)
  const int nch = nbuck;                                 // 391 (src chunks)
  const int padrows = nch * NBx;                         // 100096
  const int epb_blocks = (int)((n_edges + EPB - 1) / EPB); // 250

  // New-path workspace layout.
  __half*       h16    = (__half*)d_ws;                        // padrows*16
  int*          gcount = (int*)((char*)d_ws + (size_t)padrows * 32);
  int*          cursor = gcount + nbuck;
  int*          basep  = cursor + nbuck;                       // nbuck+1
  unsigned int* ebuf   = (unsigned int*)(basep + nbuck + 1);   // E u32
  int*          coffG  = (int*)(ebuf + n_edges);               // nbuck*400

  size_t need = (size_t)padrows * 32 + (3ull * nbuck + 1) * 4
              + (size_t)n_edges * 4 + (size_t)nbuck * 400 * 4;

  if (ws_size >= need && nbuck <= MAXBUCK) {
    // sort-by-dst-bucket -> chunk-sort -> pipelined streaming aggregation
    mlp16_kernel<<<node_blocks, 256, 0, stream>>>(
        x, w1, b1, w2, b2, wr, bl, h16, out, gcount, nbuck, n_nodes);
    hist_kernel<<<epb_blocks, 1024, 0, stream>>>(dst, gcount, nbuck,
                                                 (int)n_edges);
    scan_kernel<<<1, 256, 0, stream>>>(gcount, basep, cursor, nbuck);
    bin_kernel<<<epb_blocks, 1024, 0, stream>>>(src, dst, cursor, ebuf,
                                                nbuck, (int)n_edges);
    csort_kernel<<<nbuck, 256, 0, stream>>>(ebuf, basep, coffG, nch);
    agg_stream_kernel<<<nbuck, 256, 0, stream>>>(h16, ebuf, basep, coffG,
                                                 wl, out, nch, n_nodes);
  } else {
    // ---- fallback: verified atomic path ----
    float* h      = (float*)d_ws;
    float* summed = h + (size_t)n_nodes * 16;
    int*   fcnt   = (int*)(summed + (size_t)n_nodes * 16);
    mlp_kernel<<<node_blocks, 256, 0, stream>>>(
        x, w1, b1, w2, b2, h, summed, fcnt, n_nodes);
    {
      long long total = n_edges * 16;
      int blocks = (int)((total + 255) / 256);
      scatter_kernel<<<blocks, 256, 0, stream>>>(src, dst, h, summed, fcnt,
                                                 n_edges);
    }
    {
      long long total = (long long)n_nodes * 32;
      int blocks = (int)((total + 255) / 256);
      out_kernel<<<blocks, 256, 0, stream>>>(h, summed, fcnt, wl, bl, wr,
                                             out, n_nodes);
    }
  }
}

// Round 16
// 611.383 us; speedup vs baseline: 1.0187x; 1.0044x over previous
//
#include <hip/hip_runtime.h>
#include <hip/hip_fp16.h>

#define D_IN_C 16
#define D_OUT_C 32
#define NBL 8                   // 256 dst nodes per bucket; 256-row src chunks
#define NBx 256
#define NBMASK 255
#define MAXBUCK 512             // >= nbuck = ceil(N/256) = 391
#define EPB 12800               // edges per block in hist/bin
#define CAPS 9216               // per-bucket edge cap (mean 8184, ~11 sigma)

// ---------------------------------------------------------------------------
// K1: h16 = fp16(relu(x@w1+b1)@w2+b2), out = bl + h@wr (fp32 root term
// precomputed so agg only adds mean@wl), zero gcount. [validated r14/r15]
// ---------------------------------------------------------------------------
__global__ __launch_bounds__(256) void mlp16_kernel(
    const float* __restrict__ x,
    const float* __restrict__ w1, const float* __restrict__ b1,
    const float* __restrict__ w2, const float* __restrict__ b2,
    const float* __restrict__ wr, const float* __restrict__ bl,
    __half* __restrict__ h16, float* __restrict__ out,
    int* __restrict__ gcount, int nbuck, int n_nodes) {
  __shared__ float sw1[256], sw2[256], swr[512];
  __shared__ float sb1[16], sb2[16], sbl[32];
  int t = threadIdx.x;
  sw1[t] = w1[t]; sw2[t] = w2[t];
  swr[t] = wr[t]; swr[t + 256] = wr[t + 256];
  if (t < 16) { sb1[t] = b1[t]; sb2[t] = b2[t]; }
  if (t < 32) sbl[t] = bl[t];
  __syncthreads();

  int n = blockIdx.x * 256 + t;
  if (n < nbuck) gcount[n] = 0;
  if (n >= n_nodes) return;

  float xi[16];
  const float4* xr = (const float4*)(x + (size_t)n * 16);
  float4 v0 = xr[0], v1 = xr[1], v2 = xr[2], v3 = xr[3];
  xi[0]=v0.x; xi[1]=v0.y; xi[2]=v0.z; xi[3]=v0.w;
  xi[4]=v1.x; xi[5]=v1.y; xi[6]=v1.z; xi[7]=v1.w;
  xi[8]=v2.x; xi[9]=v2.y; xi[10]=v2.z; xi[11]=v2.w;
  xi[12]=v3.x; xi[13]=v3.y; xi[14]=v3.z; xi[15]=v3.w;

  float t1[16];
#pragma unroll
  for (int j = 0; j < 16; ++j) {
    float acc = sb1[j];
#pragma unroll
    for (int kk = 0; kk < 16; ++kk) acc += xi[kk] * sw1[kk * 16 + j];
    t1[j] = fmaxf(acc, 0.0f);
  }
  float hh[16];
#pragma unroll
  for (int j = 0; j < 16; ++j) {
    float acc = sb2[j];
#pragma unroll
    for (int kk = 0; kk < 16; ++kk) acc += t1[kk] * sw2[kk * 16 + j];
    hh[j] = acc;
  }

  unsigned int pk[8];
#pragma unroll
  for (int j = 0; j < 8; ++j) {
    unsigned lo = __half_as_ushort(__float2half(hh[2 * j]));
    unsigned hi = __half_as_ushort(__float2half(hh[2 * j + 1]));
    pk[j] = lo | (hi << 16);
  }
  uint4* hw = (uint4*)(h16 + (size_t)n * 16);
  hw[0] = make_uint4(pk[0], pk[1], pk[2], pk[3]);
  hw[1] = make_uint4(pk[4], pk[5], pk[6], pk[7]);

  float r[32];
#pragma unroll
  for (int j = 0; j < 32; ++j) r[j] = sbl[j];
#pragma unroll
  for (int kk = 0; kk < 16; ++kk) {
    float hv = hh[kk];
#pragma unroll
    for (int j = 0; j < 32; ++j) r[j] += hv * swr[kk * 32 + j];
  }
  float4* ow = (float4*)(out + (size_t)n * 32);
#pragma unroll
  for (int q = 0; q < 8; ++q)
    ow[q] = make_float4(r[4 * q], r[4 * q + 1], r[4 * q + 2], r[4 * q + 3]);
}

// ---------------------------------------------------------------------------
// K2: per-bucket histogram (dst >> 8), LDS-aggregated per block.
// ---------------------------------------------------------------------------
__global__ __launch_bounds__(1024) void hist_kernel(
    const int* __restrict__ dst, int* __restrict__ gcount,
    int nbuck, int n_edges) {
  __shared__ int lcnt[MAXBUCK];
  int t = threadIdx.x;
  for (int i = t; i < MAXBUCK; i += 1024) lcnt[i] = 0;
  __syncthreads();
  int e0 = blockIdx.x * EPB;
  int e1 = e0 + EPB; if (e1 > n_edges) e1 = n_edges;
  for (int e = e0 + t; e < e1; e += 1024)
    atomicAdd(&lcnt[dst[e] >> NBL], 1);
  __syncthreads();
  for (int b = t; b < nbuck; b += 1024) {
    int c = lcnt[b];
    if (c) atomicAdd(&gcount[b], c);
  }
}

// ---------------------------------------------------------------------------
// K3: single-block exclusive scan over nbuck bucket counts.
// ---------------------------------------------------------------------------
__global__ __launch_bounds__(256) void scan_kernel(
    const int* __restrict__ gcount, int* __restrict__ base,
    int* __restrict__ cursor, int nbuck) {
  __shared__ int ps[256];
  int t = threadIdx.x;
  int per = (nbuck + 255) / 256;
  int beg = t * per;
  int end = beg + per; if (end > nbuck) end = nbuck;
  int sum = 0;
  for (int i = beg; i < end; ++i) sum += gcount[i];
  ps[t] = sum;
  __syncthreads();
#pragma unroll
  for (int off = 1; off < 256; off <<= 1) {
    int add = (t >= off) ? ps[t - off] : 0;
    __syncthreads();
    ps[t] += add;
    __syncthreads();
  }
  int run = ps[t] - sum;
  for (int i = beg; i < end; ++i) {
    base[i] = run;
    cursor[i] = run;
    run += gcount[i];
  }
  if (t == 255) base[nbuck] = ps[255];
}

// ---------------------------------------------------------------------------
// K4: bin edges by dst-bucket. pack = (src << 8) | (dst & 255), 25 bits.
// ---------------------------------------------------------------------------
__global__ __launch_bounds__(1024) void bin_kernel(
    const int* __restrict__ src, const int* __restrict__ dst,
    int* __restrict__ cursor, unsigned int* __restrict__ ebuf,
    int nbuck, int n_edges) {
  __shared__ int lcnt[MAXBUCK];
  __shared__ int lspan[MAXBUCK];
  int t = threadIdx.x;
  for (int i = t; i < MAXBUCK; i += 1024) lcnt[i] = 0;
  __syncthreads();
  int e0 = blockIdx.x * EPB;
  int e1 = e0 + EPB; if (e1 > n_edges) e1 = n_edges;
  for (int e = e0 + t; e < e1; e += 1024)
    atomicAdd(&lcnt[dst[e] >> NBL], 1);
  __syncthreads();
  for (int b = t; b < nbuck; b += 1024) {
    int c = lcnt[b];
    lspan[b] = c ? atomicAdd(&cursor[b], c) : 0;
    lcnt[b] = 0;
  }
  __syncthreads();
  for (int e = e0 + t; e < e1; e += 1024) {
    int d = dst[e];
    int b = d >> NBL;
    int r = atomicAdd(&lcnt[b], 1);
    ebuf[lspan[b] + r] =
        ((unsigned int)src[e] << NBL) | (unsigned int)(d & NBMASK);
  }
}

// ---------------------------------------------------------------------------
// K4b: per-bucket chunk-sort -> compressed u16 list in place + per-chunk
// offsets to coffG. [validated r15]
// ---------------------------------------------------------------------------
__global__ __launch_bounds__(256) void csort_kernel(
    unsigned int* __restrict__ ebuf, const int* __restrict__ base,
    int* __restrict__ coffG, int nch) {
  __shared__ unsigned short eS2[CAPS];   // 18432 B
  __shared__ int ccnt[392];
  __shared__ int coffL[393];
  int t = threadIdx.x;
  int b = blockIdx.x;
  int beg = base[b], end = base[b + 1];
  int ne = end - beg;

  for (int i = t; i < 392; i += 256) ccnt[i] = 0;
  __syncthreads();

  if (ne > CAPS) {                       // ~11 sigma; agg uses gather fallback
    if (t == 0) coffG[b * 400 + 399] = 1;
    return;
  }
  for (int i = t; i < ne; i += 256)
    atomicAdd(&ccnt[ebuf[beg + i] >> 16], 1);
  __syncthreads();
  if (t == 0) {
    int run = 0;
    for (int c = 0; c < nch; ++c) {
      int cc = ccnt[c];
      coffL[c] = run;
      ccnt[c] = run;                     // reuse as cursor
      run += cc;
    }
    coffL[nch] = run;
  }
  __syncthreads();
  for (int i = t; i < ne; i += 256) {
    unsigned int ee = ebuf[beg + i];
    int c = (int)(ee >> 16);
    int r = atomicAdd(&ccnt[c], 1);
    eS2[r] = (unsigned short)(ee & 0xFFFFu);
  }
  __syncthreads();
  unsigned short* d16 = (unsigned short*)ebuf + (size_t)2 * beg;
  unsigned int* d32 = (unsigned int*)d16;
  int np = ne >> 1;
  for (int i = t; i < np; i += 256)
    d32[i] = (unsigned)eS2[2 * i] | ((unsigned)eS2[2 * i + 1] << 16);
  if ((ne & 1) && t == 0) d16[ne - 1] = eS2[ne - 1];
  for (int i = t; i <= nch; i += 256) coffG[b * 400 + i] = coffL[i];
  if (t == 0) coffG[b * 400 + 399] = 0;
}

// ---------------------------------------------------------------------------
// K5: depth-3 pipelined streaming aggregate. vs r15 (461us, 2500cyc/round):
//  (1) ONE barrier per round. The end-of-round barrier certifies BOTH
//      "all waves done reading buf[c%3]" and "all waves' chunk-c+1 loads
//      retired" (each wave vmcnt's BEFORE the barrier) -> next round can
//      process c+1 immediately.
//  (2) TRIPLE buffer: the chunk being waited on was issued ~2.5 rounds ago
//      (r15: ~1 round), so L2 latency is fully hidden.
//  (3) swl removed from static LDS (wl staged into the dead stream buffer
//      for the epilogue): 62KB -> still 2 blocks/CU, all 391 co-resident.
// Protocol: prologue issue {0,1,2}, vmcnt(4), barrier.
//   round c: process(c); [c<nch-1:] vmcnt(2|0); s_barrier; issue(c+3).
// ---------------------------------------------------------------------------
__global__ __launch_bounds__(256) void agg_stream_kernel(
    const __half* __restrict__ h16, const unsigned int* __restrict__ ebuf,
    const int* __restrict__ base, const int* __restrict__ coffG,
    const float* __restrict__ wl, float* __restrict__ out,
    int nch, int n_nodes) {
  __shared__ unsigned short entL[CAPS];            // 18432 B
  __shared__ __align__(16) __half bufs[3 * 4096];  // 24576 B (3 x 8KB)
  __shared__ float ssum[NBx * 16];                 // 16384 B
  __shared__ int   scnt[NBx];                      // 1024 B
  __shared__ int   coff[393];                      // 1572 B
                                                   // total 61988 B

  int t = threadIdx.x;
  int b = blockIdx.x;
  int beg = base[b], end = base[b + 1];
  int ne = end - beg;

#pragma unroll
  for (int i = t; i < NBx * 16; i += 256) ssum[i] = 0.0f;
  scnt[t] = 0;
  int flag = coffG[b * 400 + 399];
  for (int i = t; i <= nch; i += 256) coff[i] = coffG[b * 400 + i];
  if (!flag) {
    const unsigned short* s16 = (const unsigned short*)ebuf + (size_t)2 * beg;
    const unsigned int* s32 = (const unsigned int*)s16;
    int np = ne >> 1;
    for (int i = t; i < np; i += 256) {
      unsigned v = s32[i];
      entL[2 * i] = (unsigned short)(v & 0xFFFFu);
      entL[2 * i + 1] = (unsigned short)(v >> 16);
    }
    if ((ne & 1) && t == 0) entL[ne - 1] = s16[ne - 1];
  }
  __syncthreads();

  int g = t >> 4, k = t & 15;
  int wid = t >> 6, lane = t & 63;

  if (flag) {
    // overflow bucket (~never): cooperative random gather on intact u32 list
    for (int p = beg + g; p < end; p += 16) {
      unsigned int ee = ebuf[p];
      unsigned int s = ee >> NBL;
      int dl = (int)(ee & NBMASK);
      float v = __half2float(h16[(size_t)s * 16 + k]);
      atomicAdd(&ssum[dl * 16 + k], v);
      if (k == 0) atomicAdd(&scnt[dl], 1);
    }
    __syncthreads();
  } else {
    const char* hb = (const char*)h16;
#define ISSUE_CHUNK(c_)                                                       \
  {                                                                           \
    unsigned cbase_ = (unsigned)(c_) * 8192u;                                 \
    unsigned bi_ = (unsigned)(c_) % 3u;                                       \
    _Pragma("unroll")                                                         \
    for (int i2 = 0; i2 < 2; ++i2) {                                          \
      const void* gp_ = (const void*)(hb + cbase_ +                           \
          (unsigned)(wid * 2048 + i2 * 1024) + (unsigned)(lane * 16));        \
      char* lp_ = ((char*)bufs) + bi_ * 8192 + wid * 2048 + i2 * 1024;        \
      __builtin_amdgcn_global_load_lds(                                       \
          (const __attribute__((address_space(1))) void*)gp_,                 \
          (__attribute__((address_space(3))) void*)lp_, 16, 0, 0);            \
    }                                                                         \
  }
    // prologue: fill the pipeline (chunks 0..2)
    ISSUE_CHUNK(0);
    if (1 < nch) ISSUE_CHUNK(1);
    if (2 < nch) ISSUE_CHUNK(2);
    {
      int live = (nch < 3 ? nch : 3) - 1;          // chunks beyond chunk 0
      if (live == 2)      asm volatile("s_waitcnt vmcnt(4)" ::: "memory");
      else if (live == 1) asm volatile("s_waitcnt vmcnt(2)" ::: "memory");
      else                asm volatile("s_waitcnt vmcnt(0)" ::: "memory");
    }
    __builtin_amdgcn_s_barrier();

    for (int c = 0; c < nch; ++c) {
      const __half* hbuf = bufs + ((unsigned)c % 3u) * 4096;
      int cb = coff[c], ce = coff[c + 1];
      for (int i = cb + g; i < ce; i += 16) {
        unsigned short e2 = entL[i];        // broadcast within group
        int sl = e2 >> 8;
        int dl = e2 & 255;
        float v = __half2float(hbuf[sl * 16 + k]);
        atomicAdd(&ssum[dl * 16 + k], v);
        if (k == 0) atomicAdd(&scnt[dl], 1);
      }
      if (c == nch - 1) break;
      // retire chunk c+1 (issued ~2.5 rounds ago); chunk c+2 may stay out
      if (c + 2 <= nch - 1) asm volatile("s_waitcnt vmcnt(2)" ::: "memory");
      else                  asm volatile("s_waitcnt vmcnt(0)" ::: "memory");
      __builtin_amdgcn_s_barrier();         // (a) buf[c%3] free (b) c+1 visible
      if (c + 3 <= nch - 1) ISSUE_CHUNK(c + 3);
    }
#undef ISSUE_CHUNK
    __syncthreads();   // full drain before epilogue reads ssum
  }

  // epilogue: out += mean @ wl  (wl staged into the now-dead stream buffer)
  float* swl = (float*)bufs;
  swl[t] = wl[t]; swl[t + 256] = wl[t + 256];
  __syncthreads();
  int j = t & 31;
  for (int nl = t >> 5; nl < NBx; nl += 8) {
    int n = b * NBx + nl;
    if (n >= n_nodes) break;
    float inv = 1.0f / fmaxf((float)scnt[nl], 1.0f);
    float acc = 0.0f;
#pragma unroll
    for (int kk = 0; kk < 16; ++kk)
      acc += ssum[nl * 16 + kk] * inv * swl[kk * 32 + j];
    out[(size_t)n * 32 + j] += acc;
  }
}

// ---------------------------------------------------------------------------
// FALLBACK PATH (verified atomic kernels) — used only if ws too small or
// bucket table exceeds MAXBUCK.
// ---------------------------------------------------------------------------
__global__ __launch_bounds__(256) void mlp_kernel(
    const float* __restrict__ x,
    const float* __restrict__ w1, const float* __restrict__ b1,
    const float* __restrict__ w2, const float* __restrict__ b2,
    float* __restrict__ h, float* __restrict__ summed, int* __restrict__ cnt,
    int n_nodes) {
  __shared__ float sw1[256];
  __shared__ float sw2[256];
  __shared__ float sb1[16];
  __shared__ float sb2[16];
  int t = threadIdx.x;
  sw1[t] = w1[t];
  sw2[t] = w2[t];
  if (t < 16) { sb1[t] = b1[t]; sb2[t] = b2[t]; }
  __syncthreads();

  int n = blockIdx.x * blockDim.x + t;
  if (n >= n_nodes) return;

  float xi[16];
  const float4* xr = (const float4*)(x + (size_t)n * 16);
  float4 v0 = xr[0], v1 = xr[1], v2 = xr[2], v3 = xr[3];
  xi[0]=v0.x; xi[1]=v0.y; xi[2]=v0.z; xi[3]=v0.w;
  xi[4]=v1.x; xi[5]=v1.y; xi[6]=v1.z; xi[7]=v1.w;
  xi[8]=v2.x; xi[9]=v2.y; xi[10]=v2.z; xi[11]=v2.w;
  xi[12]=v3.x; xi[13]=v3.y; xi[14]=v3.z; xi[15]=v3.w;

  float t1[16];
#pragma unroll
  for (int j = 0; j < 16; ++j) {
    float acc = sb1[j];
#pragma unroll
    for (int kk = 0; kk < 16; ++kk) acc += xi[kk] * sw1[kk * 16 + j];
    t1[j] = fmaxf(acc, 0.0f);
  }
  float hh[16];
#pragma unroll
  for (int j = 0; j < 16; ++j) {
    float acc = sb2[j];
#pragma unroll
    for (int kk = 0; kk < 16; ++kk) acc += t1[kk] * sw2[kk * 16 + j];
    hh[j] = acc;
  }

  float4* hw = (float4*)(h + (size_t)n * 16);
  hw[0] = make_float4(hh[0], hh[1], hh[2], hh[3]);
  hw[1] = make_float4(hh[4], hh[5], hh[6], hh[7]);
  hw[2] = make_float4(hh[8], hh[9], hh[10], hh[11]);
  hw[3] = make_float4(hh[12], hh[13], hh[14], hh[15]);

  cnt[n] = 0;
  float4* sz = (float4*)(summed + (size_t)n * 16);
  float4 z = make_float4(0.f, 0.f, 0.f, 0.f);
  sz[0] = z; sz[1] = z; sz[2] = z; sz[3] = z;
}

__global__ __launch_bounds__(256) void scatter_kernel(
    const int* __restrict__ src, const int* __restrict__ dst,
    const float* __restrict__ h, float* __restrict__ summed,
    int* __restrict__ cnt, long long n_edges) {
  long long tid = (long long)blockIdx.x * blockDim.x + threadIdx.x;
  long long e = tid >> 4;
  int k = (int)(tid & 15);
  if (e >= n_edges) return;
  int s = src[e];
  int d = dst[e];
  float val = h[(size_t)s * 16 + k];
  atomicAdd(&summed[(size_t)d * 16 + k], val);
  if (k == 0) atomicAdd(&cnt[d], 1);
}

__global__ __launch_bounds__(256) void out_kernel(
    const float* __restrict__ h, const float* __restrict__ summed,
    const int* __restrict__ cnt,
    const float* __restrict__ wl, const float* __restrict__ bl,
    const float* __restrict__ wr, float* __restrict__ out, int n_nodes) {
  __shared__ float swl[512];
  __shared__ float swr[512];
  __shared__ float sbl[32];
  int t = threadIdx.x;
  for (int i = t; i < 512; i += 256) { swl[i] = wl[i]; swr[i] = wr[i]; }
  if (t < 32) sbl[t] = bl[t];
  __syncthreads();

  int gid = blockIdx.x * 256 + t;
  int n = gid >> 5;
  int j = gid & 31;
  if (n >= n_nodes) return;

  float inv = 1.0f / fmaxf((float)cnt[n], 1.0f);
  const float* hr = h + (size_t)n * 16;
  const float* sr = summed + (size_t)n * 16;
  float acc = sbl[j];
#pragma unroll
  for (int kk = 0; kk < 16; ++kk) {
    acc += sr[kk] * inv * swl[kk * 32 + j] + hr[kk] * swr[kk * 32 + j];
  }
  out[(size_t)n * 32 + j] = acc;
}

// ---------------------------------------------------------------------------
extern "C" void kernel_launch(void* const* d_in, const int* in_sizes, int n_in,
                              void* d_out, int out_size, void* d_ws, size_t ws_size,
                              hipStream_t stream) {
  const float* x  = (const float*)d_in[0];
  const int* eidx = (const int*)d_in[1];
  const float* w1 = (const float*)d_in[2];
  const float* b1 = (const float*)d_in[3];
  const float* w2 = (const float*)d_in[4];
  const float* b2 = (const float*)d_in[5];
  const float* wl = (const float*)d_in[6];
  const float* bl = (const float*)d_in[7];
  const float* wr = (const float*)d_in[8];
  float* out = (float*)d_out;

  const int n_nodes = in_sizes[0] / D_IN_C;             // 100000
  const long long n_edges = (long long)in_sizes[1] / 2; // 3200000
  const int* src = eidx;
  const int* dst = eidx + n_edges;

  const int node_blocks = (n_nodes + 255) / 256;         // 391
  const int nbuck = (n_nodes + NBx - 1) / NBx;           // 391 (buckets)
  const int nch = nbuck;                                 // 391 (src chunks)
  const int padrows = nch * NBx;                         // 100096
  const int epb_blocks = (int)((n_edges + EPB - 1) / EPB); // 250

  // New-path workspace layout.
  __half*       h16    = (__half*)d_ws;                        // padrows*16
  int*          gcount = (int*)((char*)d_ws + (size_t)padrows * 32);
  int*          cursor = gcount + nbuck;
  int*          basep  = cursor + nbuck;                       // nbuck+1
  unsigned int* ebuf   = (unsigned int*)(basep + nbuck + 1);   // E u32
  int*          coffG  = (int*)(ebuf + n_edges);               // nbuck*400

  size_t need = (size_t)padrows * 32 + (3ull * nbuck + 1) * 4
              + (size_t)n_edges * 4 + (size_t)nbuck * 400 * 4;

  if (ws_size >= need && nbuck <= MAXBUCK) {
    // sort-by-dst-bucket -> chunk-sort -> depth-3 pipelined streaming agg
    mlp16_kernel<<<node_blocks, 256, 0, stream>>>(
        x, w1, b1, w2, b2, wr, bl, h16, out, gcount, nbuck, n_nodes);
    hist_kernel<<<epb_blocks, 1024, 0, stream>>>(dst, gcount, nbuck,
                                                 (int)n_edges);
    scan_kernel<<<1, 256, 0, stream>>>(gcount, basep, cursor, nbuck);
    bin_kernel<<<epb_blocks, 1024, 0, stream>>>(src, dst, cursor, ebuf,
                                                nbuck, (int)n_edges);
    csort_kernel<<<nbuck, 256, 0, stream>>>(ebuf, basep, coffG, nch);
    agg_stream_kernel<<<nbuck, 256, 0, stream>>>(h16, ebuf, basep, coffG,
                                                 wl, out, nch, n_nodes);
  } else {
    // ---- fallback: verified atomic path ----
    float* h      = (float*)d_ws;
    float* summed = h + (size_t)n_nodes * 16;
    int*   fcnt   = (int*)(summed + (size_t)n_nodes * 16);
    mlp_kernel<<<node_blocks, 256, 0, stream>>>(
        x, w1, b1, w2, b2, h, summed, fcnt, n_nodes);
    {
      long long total = n_edges * 16;
      int blocks = (int)((total + 255) / 256);
      scatter_kernel<<<blocks, 256, 0, stream>>>(src, dst, h, summed, fcnt,
                                                 n_edges);
    }
    {
      long long total = (long long)n_nodes * 32;
      int blocks = (int)((total + 255) / 256);
      out_kernel<<<blocks, 256, 0, stream>>>(h, summed, fcnt, wl, bl, wr,
                                             out, n_nodes);
    }
  }
}